// Round 2
// baseline (487.741 us; speedup 1.0000x reference)
//
#include <hip/hip_runtime.h>
#include <hip/hip_bf16.h>
#include <math.h>

#define LQN 1024
#define LKN 1024
#define NB 16
#define DM 160
#define NHEADS 8
#define HDIM 20

typedef __attribute__((ext_vector_type(8))) short bf16x8;
typedef __attribute__((ext_vector_type(4))) float f32x4;

union F8 { bf16x8 v; unsigned short s[8]; unsigned int u[4]; };

__device__ __forceinline__ float bf2f(unsigned short h) {
  union { unsigned int u; float f; } c; c.u = ((unsigned int)h) << 16; return c.f;
}
__device__ __forceinline__ unsigned short f2bf(float f) {
  union { float f; unsigned int u; } c; c.f = f;
  unsigned int lsb = (c.u >> 16) & 1u;
  unsigned int r = c.u + 0x7fffu + lsb;
  return (unsigned short)(r >> 16);
}

// ---------------- f32 -> bf16 convert (weights, once per launch) ----------
__global__ void cvt_kernel(const float* __restrict__ x,
                           unsigned short* __restrict__ y, int n) {
  int i = blockIdx.x * 256 + threadIdx.x;
  if (i < n) y[i] = f2bf(x[i]);
}

// ---------------- LayerNorm over D=160, one wave per row ----------------
// x: f32, g/b: f32, y: bf16
__global__ void ln_kernel(const float* __restrict__ x,
                          const float* __restrict__ g,
                          const float* __restrict__ b,
                          unsigned short* __restrict__ y, int rows) {
  int row = blockIdx.x * 4 + (threadIdx.x >> 6);
  int lane = threadIdx.x & 63;
  const float* xr = x + (size_t)row * DM;
  float a0 = xr[lane];
  float a1 = xr[lane + 64];
  float a2 = (lane < 32) ? xr[lane + 128] : 0.0f;
  float s = a0 + a1 + a2;
#pragma unroll
  for (int m = 1; m < 64; m <<= 1) s += __shfl_xor(s, m);
  float mean = s * (1.0f / DM);
  float d0 = a0 - mean, d1 = a1 - mean, d2 = a2 - mean;
  float vs = d0 * d0 + d1 * d1 + ((lane < 32) ? d2 * d2 : 0.0f);
#pragma unroll
  for (int m = 1; m < 64; m <<= 1) vs += __shfl_xor(vs, m);
  float rstd = rsqrtf(vs * (1.0f / DM) + 1e-5f);
  unsigned short* yr = y + (size_t)row * DM;
  yr[lane]      = f2bf(d0 * rstd * g[lane]      + b[lane]);
  yr[lane + 64] = f2bf(d1 * rstd * g[lane + 64] + b[lane + 64]);
  if (lane < 32)
    yr[lane + 128] = f2bf(d2 * rstd * g[lane + 128] + b[lane + 128]);
}

// ---------------- GEMM: out[M,N] = A[M,K] @ W[N,K]^T + bias (+res/+gelu) ----
// A, W: bf16. bias, res: f32. out: bf16 (EPI 0/2) or f32 (EPI 1).
// block: 256 thr = 4 waves (2x2), wave tile 32x32, MFMA 16x16x32 bf16.
// N % 32 == 0, K % 32 == 0, M % 64 == 0. grid = (M/64, ceil(N/64)).
template <int EPI>  // 0: bias->bf16  1: bias+res->f32  2: bias+gelu->bf16
__global__ void gemm_kernel(const unsigned short* __restrict__ A,
                            const unsigned short* __restrict__ W,
                            const float* __restrict__ bias,
                            const float* __restrict__ res,
                            void* __restrict__ outp, int N, int K) {
  int lane = threadIdx.x & 63;
  int wid = threadIdx.x >> 6;
  int wr = wid >> 1, wc = wid & 1;
  int r0 = blockIdx.x * 64 + wr * 32;
  int c0 = blockIdx.y * 64 + wc * 32;
  if (c0 >= N) return;
  int lr = lane & 15;
  int ko = (lane >> 4) * 8;
  const unsigned short* Ap0 = A + (size_t)(r0 + lr) * K + ko;
  const unsigned short* Ap1 = Ap0 + (size_t)16 * K;
  const unsigned short* Wp0 = W + (size_t)(c0 + lr) * K + ko;
  const unsigned short* Wp1 = Wp0 + (size_t)16 * K;
  f32x4 acc00 = {0, 0, 0, 0}, acc01 = {0, 0, 0, 0};
  f32x4 acc10 = {0, 0, 0, 0}, acc11 = {0, 0, 0, 0};
  for (int k = 0; k < K; k += 32) {
    bf16x8 a0 = *(const bf16x8*)(Ap0 + k);
    bf16x8 a1 = *(const bf16x8*)(Ap1 + k);
    bf16x8 b0 = *(const bf16x8*)(Wp0 + k);
    bf16x8 b1 = *(const bf16x8*)(Wp1 + k);
    acc00 = __builtin_amdgcn_mfma_f32_16x16x32_bf16(a0, b0, acc00, 0, 0, 0);
    acc01 = __builtin_amdgcn_mfma_f32_16x16x32_bf16(a0, b1, acc01, 0, 0, 0);
    acc10 = __builtin_amdgcn_mfma_f32_16x16x32_bf16(a1, b0, acc10, 0, 0, 0);
    acc11 = __builtin_amdgcn_mfma_f32_16x16x32_bf16(a1, b1, acc11, 0, 0, 0);
  }
  float bc0 = bias[c0 + lr];
  float bc1 = bias[c0 + 16 + lr];
  int rb = (lane >> 4) * 4;
#pragma unroll
  for (int i = 0; i < 2; ++i) {
    f32x4 aA = i ? acc10 : acc00;
    f32x4 aB = i ? acc11 : acc01;
#pragma unroll
    for (int r = 0; r < 4; ++r) {
      int row = r0 + i * 16 + rb + r;
      float v0 = aA[r] + bc0;
      float v1 = aB[r] + bc1;
      if (EPI == 2) {
        v0 = 0.5f * v0 * (1.0f + erff(v0 * 0.70710678118654752f));
        v1 = 0.5f * v1 * (1.0f + erff(v1 * 0.70710678118654752f));
      }
      if (EPI == 1) {
        float* out = (float*)outp;
        out[(size_t)row * N + c0 + lr]      = v0 + res[(size_t)row * N + c0 + lr];
        out[(size_t)row * N + c0 + 16 + lr] = v1 + res[(size_t)row * N + c0 + 16 + lr];
      } else {
        unsigned short* out = (unsigned short*)outp;
        out[(size_t)row * N + c0 + lr] = f2bf(v0);
        out[(size_t)row * N + c0 + 16 + lr] = f2bf(v1);
      }
    }
  }
}

// ------------- head-dim fragment load with HD=20 zero padding -------------
__device__ __forceinline__ bf16x8 load_hd(const unsigned short* p, int ko) {
  F8 f;
  f.u[0] = 0; f.u[1] = 0; f.u[2] = 0; f.u[3] = 0;
  if (ko < 16) {
    f.u[0] = *(const unsigned int*)(p + ko);
    f.u[1] = *(const unsigned int*)(p + ko + 2);
    f.u[2] = *(const unsigned int*)(p + ko + 4);
    f.u[3] = *(const unsigned int*)(p + ko + 6);
  } else if (ko == 16) {
    f.u[0] = *(const unsigned int*)(p + 16);
    f.u[1] = *(const unsigned int*)(p + 18);
  }
  return f.v;
}

// ---------------- flash attention, HD=20 (padded to 32) ----------------
// Q,K,V,O: bf16. grid: (LQ/64, B*NH); block 256 = 4 waves, 16 q-rows/wave.
__global__ void attn_kernel(const unsigned short* __restrict__ Q, int ldq,
                            const unsigned short* __restrict__ K, int ldk,
                            const unsigned short* __restrict__ V, int ldv,
                            unsigned short* __restrict__ O, int ldo,
                            const float* __restrict__ tau_ptr,
                            float base_scale) {
  __shared__ unsigned short plds[4][16 * 32];
  int lane = threadIdx.x & 63;
  int wid = threadIdx.x >> 6;
  int bh = blockIdx.y;
  int b = bh >> 3, h = bh & 7;
  int q0 = blockIdx.x * 64 + wid * 16;
  float scale = base_scale;
  if (tau_ptr) {
    float lt = tau_ptr[0];
    float sp = (lt > 20.0f) ? lt : log1pf(expf(lt));
    float tau = fminf(sp + 0.5f, 2.0f);
    scale /= tau;
  }
  int lr = lane & 15;
  int lkg = lane >> 4;
  int ko = lkg * 8;
  const size_t qbase = (size_t)b * LQN;
  const size_t kbase = (size_t)b * LKN;
  bf16x8 aq = load_hd(Q + (qbase + q0 + lr) * ldq + h * HDIM, ko);
  f32x4 o0 = {0, 0, 0, 0}, o1 = {0, 0, 0, 0};
  float mrow[4], lsum[4];
#pragma unroll
  for (int r = 0; r < 4; ++r) { mrow[r] = -3.0e38f; lsum[r] = 0.0f; }
  unsigned short* pw = plds[wid];
  const f32x4 zero = {0, 0, 0, 0};
  for (int kt = 0; kt < LKN; kt += 32) {
    bf16x8 bk0 = load_hd(K + (kbase + kt + lr) * ldk + h * HDIM, ko);
    bf16x8 bk1 = load_hd(K + (kbase + kt + 16 + lr) * ldk + h * HDIM, ko);
    f32x4 s0 = __builtin_amdgcn_mfma_f32_16x16x32_bf16(aq, bk0, zero, 0, 0, 0);
    f32x4 s1 = __builtin_amdgcn_mfma_f32_16x16x32_bf16(aq, bk1, zero, 0, 0, 0);
    float p0[4], p1[4];
#pragma unroll
    for (int r = 0; r < 4; ++r) {
      s0[r] *= scale; s1[r] *= scale;
      float tm = fmaxf(s0[r], s1[r]);
#pragma unroll
      for (int m = 1; m < 16; m <<= 1) tm = fmaxf(tm, __shfl_xor(tm, m));
      float mnew = fmaxf(mrow[r], tm);
      float fac = expf(mrow[r] - mnew);
      p0[r] = expf(s0[r] - mnew);
      p1[r] = expf(s1[r] - mnew);
      float rs = p0[r] + p1[r];
#pragma unroll
      for (int m = 1; m < 16; m <<= 1) rs += __shfl_xor(rs, m);
      lsum[r] = lsum[r] * fac + rs;
      o0[r] *= fac; o1[r] *= fac;
      mrow[r] = mnew;
    }
#pragma unroll
    for (int r = 0; r < 4; ++r) {
      pw[(lkg * 4 + r) * 32 + lr] = f2bf(p0[r]);
      pw[(lkg * 4 + r) * 32 + 16 + lr] = f2bf(p1[r]);
    }
    __syncthreads();
    bf16x8 pa = *(const bf16x8*)(pw + lr * 32 + ko);
    const unsigned short* vp = V + (kbase + kt + ko) * ldv + h * HDIM;
    F8 fv0, fv1;
#pragma unroll
    for (int j = 0; j < 8; ++j) {
      fv0.s[j] = vp[(size_t)j * ldv + lr];
      fv1.s[j] = (lr < 4) ? vp[(size_t)j * ldv + 16 + lr] : (unsigned short)0;
    }
    o0 = __builtin_amdgcn_mfma_f32_16x16x32_bf16(pa, fv0.v, o0, 0, 0, 0);
    o1 = __builtin_amdgcn_mfma_f32_16x16x32_bf16(pa, fv1.v, o1, 0, 0, 0);
    __syncthreads();
  }
  unsigned short* ob = O + (qbase + q0) * ldo + h * HDIM;
#pragma unroll
  for (int r = 0; r < 4; ++r) {
    int qr = lkg * 4 + r;
    float inv = 1.0f / lsum[r];
    ob[(size_t)qr * ldo + lr] = f2bf(o0[r] * inv);
    if (lr < 4) ob[(size_t)qr * ldo + 16 + lr] = f2bf(o1[r] * inv);
  }
}

extern "C" void kernel_launch(void* const* d_in, const int* in_sizes, int n_in,
                              void* d_out, int out_size, void* d_ws, size_t ws_size,
                              hipStream_t stream) {
  (void)in_sizes; (void)n_in; (void)out_size; (void)ws_size;
  const float* q        = (const float*)d_in[0];
  const float* kv       = (const float*)d_in[1];
  const float* ln1_g    = (const float*)d_in[2];
  const float* ln1_b    = (const float*)d_in[3];
  const float* sa_in_w  = (const float*)d_in[4];
  const float* sa_in_b  = (const float*)d_in[5];
  const float* sa_out_w = (const float*)d_in[6];
  const float* sa_out_b = (const float*)d_in[7];
  const float* ln2_g    = (const float*)d_in[8];
  const float* ln2_b    = (const float*)d_in[9];
  const float* lnkv_g   = (const float*)d_in[10];
  const float* lnkv_b   = (const float*)d_in[11];
  const float* ca_qw    = (const float*)d_in[12];
  const float* ca_qb    = (const float*)d_in[13];
  const float* ca_kw    = (const float*)d_in[14];
  const float* ca_kb    = (const float*)d_in[15];
  const float* ca_vw    = (const float*)d_in[16];
  const float* ca_vb    = (const float*)d_in[17];
  const float* ca_ow    = (const float*)d_in[18];
  const float* ca_ob    = (const float*)d_in[19];
  const float* log_tau  = (const float*)d_in[20];
  const float* lnf_g    = (const float*)d_in[21];
  const float* lnf_b    = (const float*)d_in[22];
  const float* w1       = (const float*)d_in[23];
  const float* b1       = (const float*)d_in[24];
  const float* w2       = (const float*)d_in[25];
  const float* b2       = (const float*)d_in[26];

  const int M = NB * LQN;  // 16384 rows
  char* ws = (char*)d_ws;
  // layout (byte offsets):
  //   wb   @ 0           819,200 B   (bf16 weights), pad to 1 MB
  //   qn   @ 1,048,576   5,242,880   bf16 [16384,160]  (reused for all LNs)
  //   qkv  @ 6,291,456   15,728,640  bf16 [16384,480]  (reused: caq/cak/cav)
  //   attn @ 22,020,096  5,242,880   bf16 [16384,160]
  //   kvn  @ 27,262,976  5,242,880   bf16 [16384,160]
  //   q1   @ 32,505,856  10,485,760  f32  [16384,160]
  //   q2   @ 42,991,616  10,485,760  f32  [16384,160]
  //   h    @ 53,477,376  20,971,520  bf16 [16384,640]  -> total 74,448,896
  unsigned short* wb   = (unsigned short*)(ws);
  unsigned short* qn   = (unsigned short*)(ws + 1048576);
  unsigned short* qkv  = (unsigned short*)(ws + 6291456);
  unsigned short* attn = (unsigned short*)(ws + 22020096);
  unsigned short* kvn  = (unsigned short*)(ws + 27262976);
  float*          q1   = (float*)(ws + 32505856);
  float*          q2   = (float*)(ws + 42991616);
  unsigned short* hbuf = (unsigned short*)(ws + 53477376);

  unsigned short* b_sa_in  = wb;            // 76800
  unsigned short* b_sa_out = wb + 76800;    // 25600
  unsigned short* b_ca_q   = wb + 102400;   // 25600
  unsigned short* b_ca_k   = wb + 128000;   // 25600
  unsigned short* b_ca_v   = wb + 153600;   // 25600
  unsigned short* b_ca_o   = wb + 179200;   // 25600
  unsigned short* b_w1     = wb + 204800;   // 102400
  unsigned short* b_w2     = wb + 307200;   // 102400

  unsigned short* caq = qkv;
  unsigned short* cak = qkv + 2621440;  // element offsets
  unsigned short* cav = qkv + 5242880;

  dim3 blk(256);
  const float isq = 0.22360679774997896f;  // 1/sqrt(20)

  // --- weight conversion (f32 -> bf16), once per launch ---
  cvt_kernel<<<dim3(300), blk, 0, stream>>>(sa_in_w, b_sa_in, 76800);
  cvt_kernel<<<dim3(100), blk, 0, stream>>>(sa_out_w, b_sa_out, 25600);
  cvt_kernel<<<dim3(100), blk, 0, stream>>>(ca_qw, b_ca_q, 25600);
  cvt_kernel<<<dim3(100), blk, 0, stream>>>(ca_kw, b_ca_k, 25600);
  cvt_kernel<<<dim3(100), blk, 0, stream>>>(ca_vw, b_ca_v, 25600);
  cvt_kernel<<<dim3(100), blk, 0, stream>>>(ca_ow, b_ca_o, 25600);
  cvt_kernel<<<dim3(400), blk, 0, stream>>>(w1, b_w1, 102400);
  cvt_kernel<<<dim3(400), blk, 0, stream>>>(w2, b_w2, 102400);

  // --- self attention block ---
  ln_kernel<<<dim3(M / 4), blk, 0, stream>>>(q, ln1_g, ln1_b, qn, M);
  gemm_kernel<0><<<dim3(M / 64, 8), blk, 0, stream>>>(qn, b_sa_in, sa_in_b, nullptr, qkv, 480, 160);
  attn_kernel<<<dim3(LQN / 64, NB * NHEADS), blk, 0, stream>>>(
      qkv, 480, qkv + 160, 480, qkv + 320, 480, attn, 160, nullptr, isq);
  gemm_kernel<1><<<dim3(M / 64, 3), blk, 0, stream>>>(attn, b_sa_out, sa_out_b, q, q1, 160, 160);

  // --- cross attention block ---
  ln_kernel<<<dim3(M / 4), blk, 0, stream>>>(q1, ln2_g, ln2_b, qn, M);
  ln_kernel<<<dim3(M / 4), blk, 0, stream>>>(kv, lnkv_g, lnkv_b, kvn, M);
  gemm_kernel<0><<<dim3(M / 64, 3), blk, 0, stream>>>(qn, b_ca_q, ca_qb, nullptr, caq, 160, 160);
  gemm_kernel<0><<<dim3(M / 64, 3), blk, 0, stream>>>(kvn, b_ca_k, ca_kb, nullptr, cak, 160, 160);
  gemm_kernel<0><<<dim3(M / 64, 3), blk, 0, stream>>>(kvn, b_ca_v, ca_vb, nullptr, cav, 160, 160);
  attn_kernel<<<dim3(LQN / 64, NB * NHEADS), blk, 0, stream>>>(
      caq, 160, cak, 160, cav, 160, attn, 160, log_tau, isq);
  gemm_kernel<1><<<dim3(M / 64, 3), blk, 0, stream>>>(attn, b_ca_o, ca_ob, q1, q2, 160, 160);

  // --- FFN ---
  ln_kernel<<<dim3(M / 4), blk, 0, stream>>>(q2, lnf_g, lnf_b, qn, M);
  gemm_kernel<2><<<dim3(M / 64, 10), blk, 0, stream>>>(qn, b_w1, b1, nullptr, hbuf, 640, 160);
  gemm_kernel<1><<<dim3(M / 64, 3), blk, 0, stream>>>(hbuf, b_w2, b2, q2, (float*)d_out, 160, 640);
}

// Round 3
// 381.073 us; speedup vs baseline: 1.2799x; 1.2799x over previous
//
#include <hip/hip_runtime.h>
#include <hip/hip_bf16.h>
#include <math.h>

#define LQN 1024
#define LKN 1024
#define NB 16
#define DM 160
#define NHEADS 8
#define HDIM 20

typedef __attribute__((ext_vector_type(8))) short bf16x8;
typedef __attribute__((ext_vector_type(4))) float f32x4;
typedef __attribute__((ext_vector_type(2))) unsigned int u32x2;

union F8 { bf16x8 v; unsigned short s[8]; unsigned int u[4]; };

__device__ __forceinline__ float bf2f(unsigned short h) {
  union { unsigned int u; float f; } c; c.u = ((unsigned int)h) << 16; return c.f;
}
__device__ __forceinline__ unsigned short f2bf(float f) {
  union { float f; unsigned int u; } c; c.f = f;
  unsigned int lsb = (c.u >> 16) & 1u;
  unsigned int r = c.u + 0x7fffu + lsb;
  return (unsigned short)(r >> 16);
}
// packed f32x2 -> bf16x2 (RNE), one VALU op
__device__ __forceinline__ unsigned int cvtpk(float a, float b) {
  unsigned int r;
  asm("v_cvt_pk_bf16_f32 %0, %1, %2" : "=v"(r) : "v"(a), "v"(b));
  return r;
}

// ---------------- f32 -> bf16 convert (weights, once per launch) ----------
__global__ void cvt_kernel(const float* __restrict__ x,
                           unsigned short* __restrict__ y, int n) {
  int i = blockIdx.x * 256 + threadIdx.x;
  if (i < n) y[i] = f2bf(x[i]);
}

// ---------------- LayerNorm over D=160, one wave per row ----------------
__global__ void ln_kernel(const float* __restrict__ x,
                          const float* __restrict__ g,
                          const float* __restrict__ b,
                          unsigned short* __restrict__ y, int rows) {
  int row = blockIdx.x * 4 + (threadIdx.x >> 6);
  int lane = threadIdx.x & 63;
  const float* xr = x + (size_t)row * DM;
  float a0 = xr[lane];
  float a1 = xr[lane + 64];
  float a2 = (lane < 32) ? xr[lane + 128] : 0.0f;
  float s = a0 + a1 + a2;
#pragma unroll
  for (int m = 1; m < 64; m <<= 1) s += __shfl_xor(s, m);
  float mean = s * (1.0f / DM);
  float d0 = a0 - mean, d1 = a1 - mean, d2 = a2 - mean;
  float vs = d0 * d0 + d1 * d1 + ((lane < 32) ? d2 * d2 : 0.0f);
#pragma unroll
  for (int m = 1; m < 64; m <<= 1) vs += __shfl_xor(vs, m);
  float rstd = rsqrtf(vs * (1.0f / DM) + 1e-5f);
  unsigned short* yr = y + (size_t)row * DM;
  yr[lane]      = f2bf(d0 * rstd * g[lane]      + b[lane]);
  yr[lane + 64] = f2bf(d1 * rstd * g[lane + 64] + b[lane + 64]);
  if (lane < 32)
    yr[lane + 128] = f2bf(d2 * rstd * g[lane + 128] + b[lane + 128]);
}

// ---------------- GEMM: out[M,N] = A[M,K] @ W[N,K]^T + bias (+res/+gelu) ----
template <int EPI>  // 0: bias->bf16  1: bias+res->f32  2: bias+gelu->bf16
__global__ void gemm_kernel(const unsigned short* __restrict__ A,
                            const unsigned short* __restrict__ W,
                            const float* __restrict__ bias,
                            const float* __restrict__ res,
                            void* __restrict__ outp, int N, int K) {
  int lane = threadIdx.x & 63;
  int wid = threadIdx.x >> 6;
  int wr = wid >> 1, wc = wid & 1;
  int r0 = blockIdx.x * 64 + wr * 32;
  int c0 = blockIdx.y * 64 + wc * 32;
  if (c0 >= N) return;
  int lr = lane & 15;
  int ko = (lane >> 4) * 8;
  const unsigned short* Ap0 = A + (size_t)(r0 + lr) * K + ko;
  const unsigned short* Ap1 = Ap0 + (size_t)16 * K;
  const unsigned short* Wp0 = W + (size_t)(c0 + lr) * K + ko;
  const unsigned short* Wp1 = Wp0 + (size_t)16 * K;
  f32x4 acc00 = {0, 0, 0, 0}, acc01 = {0, 0, 0, 0};
  f32x4 acc10 = {0, 0, 0, 0}, acc11 = {0, 0, 0, 0};
  for (int k = 0; k < K; k += 32) {
    bf16x8 a0 = *(const bf16x8*)(Ap0 + k);
    bf16x8 a1 = *(const bf16x8*)(Ap1 + k);
    bf16x8 b0 = *(const bf16x8*)(Wp0 + k);
    bf16x8 b1 = *(const bf16x8*)(Wp1 + k);
    acc00 = __builtin_amdgcn_mfma_f32_16x16x32_bf16(a0, b0, acc00, 0, 0, 0);
    acc01 = __builtin_amdgcn_mfma_f32_16x16x32_bf16(a0, b1, acc01, 0, 0, 0);
    acc10 = __builtin_amdgcn_mfma_f32_16x16x32_bf16(a1, b0, acc10, 0, 0, 0);
    acc11 = __builtin_amdgcn_mfma_f32_16x16x32_bf16(a1, b1, acc11, 0, 0, 0);
  }
  float bc0 = bias[c0 + lr];
  float bc1 = bias[c0 + 16 + lr];
  int rb = (lane >> 4) * 4;
#pragma unroll
  for (int i = 0; i < 2; ++i) {
    f32x4 aA = i ? acc10 : acc00;
    f32x4 aB = i ? acc11 : acc01;
#pragma unroll
    for (int r = 0; r < 4; ++r) {
      int row = r0 + i * 16 + rb + r;
      float v0 = aA[r] + bc0;
      float v1 = aB[r] + bc1;
      if (EPI == 2) {
        v0 = 0.5f * v0 * (1.0f + erff(v0 * 0.70710678118654752f));
        v1 = 0.5f * v1 * (1.0f + erff(v1 * 0.70710678118654752f));
      }
      if (EPI == 1) {
        float* out = (float*)outp;
        out[(size_t)row * N + c0 + lr]      = v0 + res[(size_t)row * N + c0 + lr];
        out[(size_t)row * N + c0 + 16 + lr] = v1 + res[(size_t)row * N + c0 + 16 + lr];
      } else {
        unsigned short* out = (unsigned short*)outp;
        out[(size_t)row * N + c0 + lr] = f2bf(v0);
        out[(size_t)row * N + c0 + 16 + lr] = f2bf(v1);
      }
    }
  }
}

// ---- GEMM with TRANSPOSED output: outT[(b*N + n)*1024 + token] ----
// rows m = b*1024 + token; requires 1024 % 64 == 0 (block within one batch).
__global__ void gemm_t_kernel(const unsigned short* __restrict__ A,
                              const unsigned short* __restrict__ W,
                              const float* __restrict__ bias,
                              unsigned short* __restrict__ outT, int N, int K) {
  int lane = threadIdx.x & 63;
  int wid = threadIdx.x >> 6;
  int wr = wid >> 1, wc = wid & 1;
  int r0 = blockIdx.x * 64 + wr * 32;
  int c0 = blockIdx.y * 64 + wc * 32;
  if (c0 >= N) return;
  int lr = lane & 15;
  int ko = (lane >> 4) * 8;
  const unsigned short* Ap0 = A + (size_t)(r0 + lr) * K + ko;
  const unsigned short* Ap1 = Ap0 + (size_t)16 * K;
  const unsigned short* Wp0 = W + (size_t)(c0 + lr) * K + ko;
  const unsigned short* Wp1 = Wp0 + (size_t)16 * K;
  f32x4 acc00 = {0, 0, 0, 0}, acc01 = {0, 0, 0, 0};
  f32x4 acc10 = {0, 0, 0, 0}, acc11 = {0, 0, 0, 0};
  for (int k = 0; k < K; k += 32) {
    bf16x8 a0 = *(const bf16x8*)(Ap0 + k);
    bf16x8 a1 = *(const bf16x8*)(Ap1 + k);
    bf16x8 b0 = *(const bf16x8*)(Wp0 + k);
    bf16x8 b1 = *(const bf16x8*)(Wp1 + k);
    acc00 = __builtin_amdgcn_mfma_f32_16x16x32_bf16(a0, b0, acc00, 0, 0, 0);
    acc01 = __builtin_amdgcn_mfma_f32_16x16x32_bf16(a0, b1, acc01, 0, 0, 0);
    acc10 = __builtin_amdgcn_mfma_f32_16x16x32_bf16(a1, b0, acc10, 0, 0, 0);
    acc11 = __builtin_amdgcn_mfma_f32_16x16x32_bf16(a1, b1, acc11, 0, 0, 0);
  }
  float bc0 = bias[c0 + lr];
  float bc1 = bias[c0 + 16 + lr];
  int rb = (lane >> 4) * 4;
  int b = r0 >> 10;
  int tok0 = (r0 & 1023) + rb;
  size_t colA = ((size_t)b * N + c0 + lr) * 1024;
  size_t colB = ((size_t)b * N + c0 + 16 + lr) * 1024;
#pragma unroll
  for (int i = 0; i < 2; ++i) {
    f32x4 aA = i ? acc10 : acc00;
    f32x4 aB = i ? acc11 : acc01;
    int t0 = tok0 + i * 16;
    *(unsigned int*)(outT + colA + t0)     = cvtpk(aA[0] + bc0, aA[1] + bc0);
    *(unsigned int*)(outT + colA + t0 + 2) = cvtpk(aA[2] + bc0, aA[3] + bc0);
    *(unsigned int*)(outT + colB + t0)     = cvtpk(aB[0] + bc1, aB[1] + bc1);
    *(unsigned int*)(outT + colB + t0 + 2) = cvtpk(aB[2] + bc1, aB[3] + bc1);
  }
}

// ------- head-dim fragment load, HD=20 zero-padded to 32, uint2 loads -------
__device__ __forceinline__ bf16x8 load_hd(const unsigned short* p, int ko) {
  F8 f;
  f.u[0] = 0; f.u[1] = 0; f.u[2] = 0; f.u[3] = 0;
  if (ko == 0) {
    u32x2 a = *(const u32x2*)(p);
    u32x2 b = *(const u32x2*)(p + 4);
    f.u[0] = a.x; f.u[1] = a.y; f.u[2] = b.x; f.u[3] = b.y;
  } else if (ko == 8) {
    u32x2 a = *(const u32x2*)(p + 8);
    u32x2 b = *(const u32x2*)(p + 12);
    f.u[0] = a.x; f.u[1] = a.y; f.u[2] = b.x; f.u[3] = b.y;
  } else if (ko == 16) {
    u32x2 a = *(const u32x2*)(p + 16);
    f.u[0] = a.x; f.u[1] = a.y;
  }
  return f.v;
}

// ---------------- flash attention, HD=20 (padded to 32), KVBLK=64 ----------
// Q,K row-major bf16 (ld given); vT layout [(b*160 + h*20 + d)][1024] bf16.
// grid: (LQ/64, B*NH); block 256 = 4 waves, 16 q-rows/wave. No barriers:
// the P tile in LDS is wave-private.
__global__ void attn_kernel(const unsigned short* __restrict__ Q, int ldq,
                            const unsigned short* __restrict__ K, int ldk,
                            const unsigned short* __restrict__ vT,
                            unsigned short* __restrict__ O, int ldo,
                            const float* __restrict__ tau_ptr,
                            float base_scale) {
  __shared__ unsigned short plds[4][16 * 72];  // [q][72] per wave, 16B-aligned rows
  int lane = threadIdx.x & 63;
  int wid = threadIdx.x >> 6;
  int bh = blockIdx.y;
  int b = bh >> 3, h = bh & 7;
  int q0 = blockIdx.x * 64 + wid * 16;
  float scale = base_scale;
  if (tau_ptr) {
    float lt = tau_ptr[0];
    float sp = (lt > 20.0f) ? lt : log1pf(expf(lt));
    float tau = fminf(sp + 0.5f, 2.0f);
    scale /= tau;
  }
  int lr = lane & 15;
  int lkg = lane >> 4;
  int ko = lkg * 8;
  int rb = lkg * 4;
  int hoff = h * HDIM;
  const size_t qbase = (size_t)b * LQN;
  bf16x8 aq = load_hd(Q + (qbase + q0 + lr) * ldq + hoff, ko);
  const unsigned short* kr = K + (qbase + lr) * ldk + hoff;
  size_t vrow = (size_t)b * DM + hoff;
  const unsigned short* vr0 = vT + (vrow + lr) * LKN;
  const unsigned short* vr1 = vT + (vrow + 16 + lr) * LKN;  // deref only if lr<4
  unsigned short* pwr = plds[wid] + rb * 72 + lr;
  const unsigned short* pra = plds[wid] + lr * 72 + ko;
  f32x4 o0 = {0, 0, 0, 0}, o1 = {0, 0, 0, 0};
  float mrow[4], lsum[4];
#pragma unroll
  for (int r = 0; r < 4; ++r) { mrow[r] = -3.0e38f; lsum[r] = 0.0f; }
  const f32x4 zero = {0, 0, 0, 0};
  for (int kt = 0; kt < LKN; kt += 64) {
    bf16x8 bk0 = load_hd(kr, ko);
    bf16x8 bk1 = load_hd(kr + (size_t)16 * ldk, ko);
    bf16x8 bk2 = load_hd(kr + (size_t)32 * ldk, ko);
    bf16x8 bk3 = load_hd(kr + (size_t)48 * ldk, ko);
    kr += (size_t)64 * ldk;
    f32x4 s0 = __builtin_amdgcn_mfma_f32_16x16x32_bf16(aq, bk0, zero, 0, 0, 0);
    f32x4 s1 = __builtin_amdgcn_mfma_f32_16x16x32_bf16(aq, bk1, zero, 0, 0, 0);
    f32x4 s2 = __builtin_amdgcn_mfma_f32_16x16x32_bf16(aq, bk2, zero, 0, 0, 0);
    f32x4 s3 = __builtin_amdgcn_mfma_f32_16x16x32_bf16(aq, bk3, zero, 0, 0, 0);
#pragma unroll
    for (int r = 0; r < 4; ++r) {
      float tm = fmaxf(fmaxf(s0[r], s1[r]), fmaxf(s2[r], s3[r]));
#pragma unroll
      for (int m = 1; m < 16; m <<= 1) tm = fmaxf(tm, __shfl_xor(tm, m));
      float mnew = fmaxf(mrow[r], tm * scale);
      float fac = __expf(mrow[r] - mnew);
      float p0 = __expf(fmaf(s0[r], scale, -mnew));
      float p1 = __expf(fmaf(s1[r], scale, -mnew));
      float p2 = __expf(fmaf(s2[r], scale, -mnew));
      float p3 = __expf(fmaf(s3[r], scale, -mnew));
      float rs = (p0 + p1) + (p2 + p3);
#pragma unroll
      for (int m = 1; m < 16; m <<= 1) rs += __shfl_xor(rs, m);
      lsum[r] = lsum[r] * fac + rs;
      o0[r] *= fac; o1[r] *= fac;
      mrow[r] = mnew;
      unsigned int pkA = cvtpk(p0, p1), pkB = cvtpk(p2, p3);
      pwr[r * 72]      = (unsigned short)pkA;
      pwr[r * 72 + 16] = (unsigned short)(pkA >> 16);
      pwr[r * 72 + 32] = (unsigned short)pkB;
      pwr[r * 72 + 48] = (unsigned short)(pkB >> 16);
    }
#pragma unroll
    for (int t = 0; t < 2; ++t) {
      bf16x8 pa = *(const bf16x8*)(pra + t * 32);
      bf16x8 vb0 = *(const bf16x8*)(vr0 + kt + t * 32 + ko);
      F8 fz; fz.u[0] = 0; fz.u[1] = 0; fz.u[2] = 0; fz.u[3] = 0;
      bf16x8 vb1 = fz.v;
      if (lr < 4) vb1 = *(const bf16x8*)(vr1 + kt + t * 32 + ko);
      o0 = __builtin_amdgcn_mfma_f32_16x16x32_bf16(pa, vb0, o0, 0, 0, 0);
      o1 = __builtin_amdgcn_mfma_f32_16x16x32_bf16(pa, vb1, o1, 0, 0, 0);
    }
  }
  unsigned short* ob = O + (qbase + q0) * ldo + hoff;
#pragma unroll
  for (int r = 0; r < 4; ++r) {
    int qr = rb + r;
    float inv = 1.0f / lsum[r];
    ob[(size_t)qr * ldo + lr] = f2bf(o0[r] * inv);
    if (lr < 4) ob[(size_t)qr * ldo + 16 + lr] = f2bf(o1[r] * inv);
  }
}

extern "C" void kernel_launch(void* const* d_in, const int* in_sizes, int n_in,
                              void* d_out, int out_size, void* d_ws, size_t ws_size,
                              hipStream_t stream) {
  (void)in_sizes; (void)n_in; (void)out_size; (void)ws_size;
  const float* q        = (const float*)d_in[0];
  const float* kv       = (const float*)d_in[1];
  const float* ln1_g    = (const float*)d_in[2];
  const float* ln1_b    = (const float*)d_in[3];
  const float* sa_in_w  = (const float*)d_in[4];
  const float* sa_in_b  = (const float*)d_in[5];
  const float* sa_out_w = (const float*)d_in[6];
  const float* sa_out_b = (const float*)d_in[7];
  const float* ln2_g    = (const float*)d_in[8];
  const float* ln2_b    = (const float*)d_in[9];
  const float* lnkv_g   = (const float*)d_in[10];
  const float* lnkv_b   = (const float*)d_in[11];
  const float* ca_qw    = (const float*)d_in[12];
  const float* ca_qb    = (const float*)d_in[13];
  const float* ca_kw    = (const float*)d_in[14];
  const float* ca_kb    = (const float*)d_in[15];
  const float* ca_vw    = (const float*)d_in[16];
  const float* ca_vb    = (const float*)d_in[17];
  const float* ca_ow    = (const float*)d_in[18];
  const float* ca_ob    = (const float*)d_in[19];
  const float* log_tau  = (const float*)d_in[20];
  const float* lnf_g    = (const float*)d_in[21];
  const float* lnf_b    = (const float*)d_in[22];
  const float* w1       = (const float*)d_in[23];
  const float* b1       = (const float*)d_in[24];
  const float* w2       = (const float*)d_in[25];
  const float* b2       = (const float*)d_in[26];

  const int M = NB * LQN;  // 16384 rows
  char* ws = (char*)d_ws;
  // layout (byte offsets), total 74,448,896 (same footprint as round 2):
  //   wb   @ 0           819,200     bf16 weights
  //   qn   @ 1,048,576   5,242,880   bf16 [16384,160] (all LN outputs)
  //   qk   @ 6,291,456   10,485,760  bf16 [16384,320] sq|sk; later caq|cak
  //   svT  @ 16,777,216  5,242,880   bf16 [2560,1024] V^T; later cavT
  //   attn @ 22,020,096  5,242,880   bf16 [16384,160]
  //   kvn  @ 27,262,976  5,242,880   bf16 [16384,160]
  //   q1   @ 32,505,856  10,485,760  f32
  //   q2   @ 42,991,616  10,485,760  f32
  //   h    @ 53,477,376  20,971,520  bf16 [16384,640]
  unsigned short* wb   = (unsigned short*)(ws);
  unsigned short* qn   = (unsigned short*)(ws + 1048576);
  unsigned short* qk   = (unsigned short*)(ws + 6291456);
  unsigned short* svT  = (unsigned short*)(ws + 16777216);
  unsigned short* attn = (unsigned short*)(ws + 22020096);
  unsigned short* kvn  = (unsigned short*)(ws + 27262976);
  float*          q1   = (float*)(ws + 32505856);
  float*          q2   = (float*)(ws + 42991616);
  unsigned short* hbuf = (unsigned short*)(ws + 53477376);

  unsigned short* b_sa_in  = wb;            // 76800
  unsigned short* b_sa_out = wb + 76800;    // 25600
  unsigned short* b_ca_q   = wb + 102400;   // 25600
  unsigned short* b_ca_k   = wb + 128000;   // 25600
  unsigned short* b_ca_v   = wb + 153600;   // 25600
  unsigned short* b_ca_o   = wb + 179200;   // 25600
  unsigned short* b_w1     = wb + 204800;   // 102400
  unsigned short* b_w2     = wb + 307200;   // 102400

  unsigned short* caq  = qk;                 // reuse after self-attn
  unsigned short* cak  = qk + 2621440;       // +5,242,880 B
  unsigned short* cavT = svT;

  dim3 blk(256);
  const float isq = 0.22360679774997896f;  // 1/sqrt(20)

  // --- weight conversion ---
  cvt_kernel<<<dim3(300), blk, 0, stream>>>(sa_in_w, b_sa_in, 76800);
  cvt_kernel<<<dim3(100), blk, 0, stream>>>(sa_out_w, b_sa_out, 25600);
  cvt_kernel<<<dim3(100), blk, 0, stream>>>(ca_qw, b_ca_q, 25600);
  cvt_kernel<<<dim3(100), blk, 0, stream>>>(ca_kw, b_ca_k, 25600);
  cvt_kernel<<<dim3(100), blk, 0, stream>>>(ca_vw, b_ca_v, 25600);
  cvt_kernel<<<dim3(100), blk, 0, stream>>>(ca_ow, b_ca_o, 25600);
  cvt_kernel<<<dim3(400), blk, 0, stream>>>(w1, b_w1, 102400);
  cvt_kernel<<<dim3(400), blk, 0, stream>>>(w2, b_w2, 102400);

  // --- self attention block ---
  ln_kernel<<<dim3(M / 4), blk, 0, stream>>>(q, ln1_g, ln1_b, qn, M);
  gemm_kernel<0><<<dim3(M / 64, 5), blk, 0, stream>>>(qn, b_sa_in, sa_in_b, nullptr, qk, 320, 160);
  gemm_t_kernel<<<dim3(M / 64, 3), blk, 0, stream>>>(qn, b_sa_in + 320 * 160, sa_in_b + 320, svT, 160, 160);
  attn_kernel<<<dim3(LQN / 64, NB * NHEADS), blk, 0, stream>>>(
      qk, 320, qk + 160, 320, svT, attn, 160, nullptr, isq);
  gemm_kernel<1><<<dim3(M / 64, 3), blk, 0, stream>>>(attn, b_sa_out, sa_out_b, q, q1, 160, 160);

  // --- cross attention block ---
  ln_kernel<<<dim3(M / 4), blk, 0, stream>>>(q1, ln2_g, ln2_b, qn, M);
  ln_kernel<<<dim3(M / 4), blk, 0, stream>>>(kv, lnkv_g, lnkv_b, kvn, M);
  gemm_kernel<0><<<dim3(M / 64, 3), blk, 0, stream>>>(qn, b_ca_q, ca_qb, nullptr, caq, 160, 160);
  gemm_kernel<0><<<dim3(M / 64, 3), blk, 0, stream>>>(kvn, b_ca_k, ca_kb, nullptr, cak, 160, 160);
  gemm_t_kernel<<<dim3(M / 64, 3), blk, 0, stream>>>(kvn, b_ca_v, ca_vb, cavT, 160, 160);
  attn_kernel<<<dim3(LQN / 64, NB * NHEADS), blk, 0, stream>>>(
      caq, 160, cak, 160, cavT, attn, 160, log_tau, isq);
  gemm_kernel<1><<<dim3(M / 64, 3), blk, 0, stream>>>(attn, b_ca_o, ca_ob, q1, q2, 160, 160);

  // --- FFN ---
  ln_kernel<<<dim3(M / 4), blk, 0, stream>>>(q2, lnf_g, lnf_b, qn, M);
  gemm_kernel<2><<<dim3(M / 64, 10), blk, 0, stream>>>(qn, b_w1, b1, nullptr, hbuf, 640, 160);
  gemm_kernel<1><<<dim3(M / 64, 3), blk, 0, stream>>>(hbuf, b_w2, b2, q2, (float*)d_out, 160, 640);
}